// Round 8
// baseline (525.231 us; speedup 1.0000x reference)
//
#include <hip/hip_runtime.h>
#include <cstdint>
#include <cstddef>

// Problem constants (B=4, V=64, E=1024, L=1024, D=256, DEG=16)
constexpr int Bv = 4;
constexpr int Ev = 1024;      // edges per batch
constexpr int Lv = 1024;
constexpr int BE = Bv * Ev;   // 4096
constexpr size_t EI_PLANE = (size_t)BE * Lv;  // 4,194,304 elements per ei plane

// S scratch row stride (fp32): 32 band cols + 1 pad -> banks spread (s*33%32=s)
constexpr int SROW = 33;

typedef __bf16 bf16x8 __attribute__((ext_vector_type(8)));
typedef __bf16 bf16x2 __attribute__((ext_vector_type(2)));
typedef float  f32x4  __attribute__((ext_vector_type(4)));

// pack two f32 -> one dword of 2 bf16 (RNE, compiler emits v_cvt_pk_bf16_f32)
static __device__ __forceinline__ unsigned int pack_bf2(float lo, float hi) {
    union { bf16x2 h; unsigned int u; } c;
    c.h[0] = (__bf16)lo; c.h[1] = (__bf16)hi;
    return c.u;
}

// load 8 consecutive fp32 from global, convert to one bf16x8 fragment
static __device__ __forceinline__ bf16x8 load_frag8(const float* p) {
    float4 a = *(const float4*)p;
    float4 b = *(const float4*)(p + 4);
    union { uint4 u; bf16x8 h; } t;
    t.u.x = pack_bf2(a.x, a.y);
    t.u.y = pack_bf2(a.z, a.w);
    t.u.z = pack_bf2(b.x, b.y);
    t.u.w = pack_bf2(b.z, b.w);
    return t.h;
}

// ---------------------------------------------------------------------------
// Precompute (grid 257 x 256 threads):
//  blocks 0..255: tile (i = blk>>4, j = blk&15) of M' = (Wq^T Wk) / 16,
//    bf16, written pre-swizzled to MFMA fragment layout (A- and B-fragment
//    layouts are identical for 16x16x32):
//      for element (d, t):  f = (d>>5)*16 + (t>>4);
//                           lane = ((d>>3)&3)*16 + (t&15); jj = d&7;
//      Mb[(f*64 + lane)*8 + jj] = M'[d][t]
//  block 256: rv[t] = (sum_i bq[i] * Wk[i*256+t]) / 16  (fp32)
//  (bk and the h_src-only bias terms cancel in the softmax -> never computed;
//   the 1/sqrt(D)=1/16 logit scale is folded in here.)
// ---------------------------------------------------------------------------
__global__ __launch_bounds__(256) void precompute_kernel(
    const float* __restrict__ Wq, const float* __restrict__ Wk,
    const float* __restrict__ bq, __bf16* __restrict__ Mb, float* __restrict__ rv)
{
    const int blk = blockIdx.x;
    const int tid = threadIdx.x;
    if (blk < 256) {
        __shared__ float qs[256 * 17];
        __shared__ float ks[256 * 17];
        const int i16 = (blk >> 4) * 16;   // d-tile base
        const int j16 = (blk & 15) * 16;   // t-tile base
        const int c  = tid & 15;
        const int r0 = tid >> 4;
        #pragma unroll
        for (int it = 0; it < 16; ++it) {
            const int r = it * 16 + r0;
            qs[r * 17 + c] = Wq[r * 256 + i16 + c];
            ks[r * 17 + c] = Wk[r * 256 + j16 + c];
        }
        __syncthreads();
        const int dd = tid >> 4;   // 0..15 local d
        const int tt = tid & 15;   // 0..15 local t
        float a0 = 0.f, a1 = 0.f, a2 = 0.f, a3 = 0.f;
        for (int r = 0; r < 256; r += 4) {
            a0 = fmaf(qs[(r + 0) * 17 + dd], ks[(r + 0) * 17 + tt], a0);
            a1 = fmaf(qs[(r + 1) * 17 + dd], ks[(r + 1) * 17 + tt], a1);
            a2 = fmaf(qs[(r + 2) * 17 + dd], ks[(r + 2) * 17 + tt], a2);
            a3 = fmaf(qs[(r + 3) * 17 + dd], ks[(r + 3) * 17 + tt], a3);
        }
        const float m = ((a0 + a1) + (a2 + a3)) * 0.0625f;
        const int d = i16 + dd, t = j16 + tt;
        const int f    = (d >> 5) * 16 + (t >> 4);
        const int lane = ((d >> 3) & 3) * 16 + (t & 15);
        const int jj   = d & 7;
        Mb[((size_t)f * 64 + lane) * 8 + jj] = (__bf16)m;
    } else {
        __shared__ float bqs[256];
        bqs[tid] = bq[tid];
        __syncthreads();
        float a0 = 0.f, a1 = 0.f;
        for (int i = 0; i < 256; i += 2) {
            a0 = fmaf(bqs[i + 0], Wk[(i + 0) * 256 + tid], a0);
            a1 = fmaf(bqs[i + 1], Wk[(i + 1) * 256 + tid], a1);
        }
        rv[tid] = (a0 + a1) * 0.0625f;
    }
}

// ---------------------------------------------------------------------------
// Main fused kernel, v-split, NO hs staging, ZERO barriers.
// One block (4 waves) per (b,l). LDS = S scratch only (8448 B).
// __launch_bounds__(256,5): target <=102 VGPR -> 5 waves/SIMD (62% occ).
// Wave w owns v-tile w (S rows 16w..16w+16, all 256 t contracted in-wave):
//  - hfrK[8] (own 16 rows) loaded DIRECTLY from global fp32 + cvt_pk
//    (identical bf16 values to the old staged path -> bitwise-same result).
//  - GEMM1 swapped per t-pair p (FULLY unrolled so hfrK[p] is static):
//    acc = Mb-frag x hfrK  (Mb addresses shared by all waves -> L1/L2 bcast)
//  - pack + permlane32/16 -> GEMM2 A-frag in registers.
//  - GEMM2 band: brow0 = hfrK[p] (free, register reuse); brow1 = partner
//    tile rows loaded from global per p (L2-hit: partner wave reads them too).
//  - S store to wave-private rows of shared S scratch; logits read back by
//    the SAME wave (src = tid/4 in [16w,16w+16)) -> no __syncthreads at all.
//  - group-of-16 softmax via 4-lane shfl; probs write (or scattered ew_out).
// ---------------------------------------------------------------------------
template <bool USE_WS>
__global__ __launch_bounds__(256, 5) void edge_main(
    const float* __restrict__ hs, const int* __restrict__ eidx,
    const float* __restrict__ ew, const float* __restrict__ skipp,
    const __bf16* __restrict__ Mb, const float* __restrict__ rv,
    float* __restrict__ probs_or_out)
{
    __shared__ float S0[64 * SROW];     // 8448 B (only LDS block)

    const int bl = blockIdx.x;          // 0..4095
    const int b  = bl >> 10;
    const int l  = bl & 1023;
    const int tid  = threadIdx.x;
    const int w    = tid >> 6;          // wave 0..3 = owned v-tile
    const int lane = tid & 63;
    const int l15  = lane & 15;
    const int quad = lane >> 4;
    const int nt1  = (w + 1) & 3;       // band partner n-tile

    // ---- hoisted per-edge indices ----
    const int e0  = tid * 4;
    const int be0 = b * Ev + e0;
    int soff[4];
    #pragma unroll
    for (int j = 0; j < 4; ++j) {
        const int src = eidx[be0 + j];
        const int dst = eidx[BE + be0 + j];
        // dst in {src+1..src+16} mod 64 -> slot in {0,1} always
        const int slot = ((dst >> 4) - (src >> 4)) & 3;
        soff[j] = src * SROW + slot * 16 + (dst & 15);
    }

    // ---- row bases: own tile row (16w + l15), partner tile row ----
    const float* rb_own = hs +
        ((size_t)(b * 64 + w * 16 + l15) * 1024 + (size_t)l) * 256;
    const float* rb_par = hs +
        ((size_t)(b * 64 + nt1 * 16 + l15) * 1024 + (size_t)l) * 256;

    // ---- persistent own-tile fragments (8 x bf16x8 = 32 VGPR) ----
    bf16x8 hfrK[8];
    #pragma unroll
    for (int kt = 0; kt < 8; ++kt)
        hfrK[kt] = load_frag8(rb_own + kt * 32 + quad * 8);

    // s_acc: slot 0 -> n-tile w, slot 1 -> n-tile (w+1)&3  (8 VGPR)
    f32x4 s_acc0, s_acc1;
    s_acc0[0] = 0.f; s_acc0[1] = 0.f; s_acc0[2] = 0.f; s_acc0[3] = 0.f;
    s_acc1 = s_acc0;

    #pragma unroll
    for (int p = 0; p < 8; ++p) {
        // ---- GEMM1 (swapped): acc[tt] over t-tiles {2p, 2p+1} ----
        // bias rv[t] per-ROW of T^T: element r gets rv[(2p+tt)*16+quad*4+r]
        f32x4 acc0 = *(const f32x4*)(rv + (2 * p + 0) * 16 + quad * 4);
        f32x4 acc1 = *(const f32x4*)(rv + (2 * p + 1) * 16 + quad * 4);
        #pragma unroll
        for (int kh = 0; kh < 4; ++kh) {
            const int kta = kh * 2, ktb = kh * 2 + 1;
            // 4 Mb fragments (addresses identical across all waves/blocks)
            const bf16x8 m0a = *(const bf16x8*)(Mb +
                ((size_t)((kta * 16 + 2 * p + 0) * 64 + lane)) * 8);
            const bf16x8 m1a = *(const bf16x8*)(Mb +
                ((size_t)((kta * 16 + 2 * p + 1) * 64 + lane)) * 8);
            const bf16x8 m0b = *(const bf16x8*)(Mb +
                ((size_t)((ktb * 16 + 2 * p + 0) * 64 + lane)) * 8);
            const bf16x8 m1b = *(const bf16x8*)(Mb +
                ((size_t)((ktb * 16 + 2 * p + 1) * 64 + lane)) * 8);
            acc0 = __builtin_amdgcn_mfma_f32_16x16x32_bf16(m0a, hfrK[kta], acc0, 0, 0, 0);
            acc1 = __builtin_amdgcn_mfma_f32_16x16x32_bf16(m1a, hfrK[kta], acc1, 0, 0, 0);
            acc0 = __builtin_amdgcn_mfma_f32_16x16x32_bf16(m0b, hfrK[ktb], acc0, 0, 0, 0);
            acc1 = __builtin_amdgcn_mfma_f32_16x16x32_bf16(m1b, hfrK[ktb], acc1, 0, 0, 0);
        }
        // ---- partner brow (global, L2-warm) ----
        const bf16x8 brow1 = load_frag8(rb_par + p * 32 + quad * 8);

        // ---- pack + permlane route -> GEMM2 A-frag (registers only) ----
        unsigned int Ar = pack_bf2(acc0[0], acc0[1]); // t = g*4+{0,1}
        unsigned int Br = pack_bf2(acc0[2], acc0[3]); // t = g*4+{2,3}
        unsigned int Cr = pack_bf2(acc1[0], acc1[1]); // t = 16+g*4+{0,1}
        unsigned int Dr = pack_bf2(acc1[2], acc1[3]); // t = 16+g*4+{2,3}
        asm("v_permlane32_swap_b32 %0, %1" : "+v"(Ar), "+v"(Cr));
        asm("v_permlane16_swap_b32 %0, %1" : "+v"(Ar), "+v"(Cr));
        asm("v_permlane32_swap_b32 %0, %1" : "+v"(Br), "+v"(Dr));
        asm("v_permlane16_swap_b32 %0, %1" : "+v"(Br), "+v"(Dr));
        union { uint4 u; bf16x8 h; } fr;
        fr.u = make_uint4(Ar, Br, Cr, Dr);   // A-frag, k = 32 t's of pair p

        // ---- GEMM2 band: rows v-tile w, n-tiles {w, (w+1)&3} ----
        // brow0 for n-tile w == hfrK[p] (p static after full unroll)
        s_acc0 = __builtin_amdgcn_mfma_f32_16x16x32_bf16(fr.h, hfrK[p], s_acc0, 0, 0, 0);
        s_acc1 = __builtin_amdgcn_mfma_f32_16x16x32_bf16(fr.h, brow1,   s_acc1, 0, 0, 0);
    }

    // ---- S store: wave-private rows; read back by SAME wave -> no barrier ----
    #pragma unroll
    for (int r = 0; r < 4; ++r) {
        S0[(w * 16 + quad * 4 + r) * SROW +  0 + l15] = s_acc0[r];
        S0[(w * 16 + quad * 4 + r) * SROW + 16 + l15] = s_acc1[r];
    }

    // ---- per-edge logits + group-of-16 softmax (src = tid/4 in own rows) ----
    float lg[4];
    #pragma unroll
    for (int j = 0; j < 4; ++j)
        lg[j] = S0[soff[j]];

    float mx = fmaxf(fmaxf(lg[0], lg[1]), fmaxf(lg[2], lg[3]));
    mx = fmaxf(mx, __shfl_xor(mx, 1));
    mx = fmaxf(mx, __shfl_xor(mx, 2));
    float ex[4], sm = 0.f;
    #pragma unroll
    for (int j = 0; j < 4; ++j) { ex[j] = __expf(lg[j] - mx); sm += ex[j]; }
    sm += __shfl_xor(sm, 1);
    sm += __shfl_xor(sm, 2);
    const float inv = 1.0f / sm;

    if (USE_WS) {
        float4 o = make_float4(ex[0] * inv, ex[1] * inv, ex[2] * inv, ex[3] * inv);
        *(float4*)(probs_or_out + (size_t)bl * 1024 + e0) = o;
    } else {
        const float skip = skipp[0];
        const float om = 1.0f - skip;
        #pragma unroll
        for (int j = 0; j < 4; ++j) {
            float g = fmaf(skip, ew[be0 + j], om * (ex[j] * inv));
            probs_or_out[(size_t)(be0 + j) * Lv + l] = g;
        }
    }
}

// ---------------------------------------------------------------------------
// Output kernel: tiled transpose of probs (b,l,e) -> ew_out (be,l), plus ei
// broadcast. Block = (lt, et, b) transposes one 64x64 tile.
// ---------------------------------------------------------------------------
__global__ __launch_bounds__(256) void output_kernel(
    const float* __restrict__ probs, const int* __restrict__ eidx,
    const float* __restrict__ ew, const float* __restrict__ skipp,
    float* __restrict__ out)
{
    __shared__ float tile[64 * 68];
    const int lt = blockIdx.x;   // 0..15
    const int et = blockIdx.y;   // 0..15
    const int b  = blockIdx.z;   // 0..3
    const int t  = threadIdx.x;
    const int tr = t >> 4;       // 0..15
    const int tc = t & 15;       // 0..15

    #pragma unroll
    for (int q = 0; q < 4; ++q) {
        const int lloc = q * 16 + tr;
        float4 v = *(const float4*)(probs +
            ((size_t)(b * 1024 + lt * 64 + lloc)) * 1024 + et * 64 + tc * 4);
        *(float4*)(&tile[lloc * 68 + tc * 4]) = v;
    }
    __syncthreads();

    const float skip = skipp[0];
    const float om = 1.0f - skip;
    float* out_ei0 = out;
    float* out_ei1 = out + EI_PLANE;
    float* out_ew  = out + 2 * EI_PLANE;

    #pragma unroll
    for (int q = 0; q < 4; ++q) {
        const int eloc = q * 16 + tr;
        const int be = b * Ev + et * 64 + eloc;
        const float w  = ew[be];
        const float sv = (float)eidx[be];
        const float dv = (float)eidx[BE + be];
        const int lloc0 = tc * 4;
        float4 o;
        o.x = fmaf(skip, w, om * tile[(lloc0 + 0) * 68 + eloc]);
        o.y = fmaf(skip, w, om * tile[(lloc0 + 1) * 68 + eloc]);
        o.z = fmaf(skip, w, om * tile[(lloc0 + 2) * 68 + eloc]);
        o.w = fmaf(skip, w, om * tile[(lloc0 + 3) * 68 + eloc]);
        const size_t off = (size_t)be * Lv + lt * 64 + lloc0;
        *(float4*)(out_ew  + off) = o;
        *(float4*)(out_ei0 + off) = make_float4(sv, sv, sv, sv);
        *(float4*)(out_ei1 + off) = make_float4(dv, dv, dv, dv);
    }
}

// Fallback ei broadcast kernel (only used if ws too small for probs buffer)
__global__ __launch_bounds__(256) void ei_kernel(
    const int* __restrict__ eidx, float* __restrict__ out)
{
    const int blk = blockIdx.x;            // 0..8191  (c*4096 + j)
    const int c = blk >> 12;
    const int j = blk & 4095;
    const float v = (float)eidx[c * BE + j];
    float4 o = make_float4(v, v, v, v);
    *(float4*)(out + (size_t)blk * 1024 + threadIdx.x * 4) = o;
}

// ---------------------------------------------------------------------------
extern "C" void kernel_launch(void* const* d_in, const int* in_sizes, int n_in,
                              void* d_out, int out_size, void* d_ws, size_t ws_size,
                              hipStream_t stream)
{
    const float* hs   = (const float*)d_in[0];
    const int*   eidx = (const int*)d_in[1];
    const float* ew   = (const float*)d_in[2];
    const float* Wq   = (const float*)d_in[3];
    const float* bq   = (const float*)d_in[4];
    const float* Wk   = (const float*)d_in[5];
    // d_in[6] = bk: provably unused (cancels in softmax)
    const float* skip = (const float*)d_in[7];

    char* wsb = (char*)d_ws;
    __bf16* Mb   = (__bf16*)wsb;                       // 65536 bf16 = 128 KiB
    float*  rv   = (float*)(wsb + 131072);             // 256 fp32 = 1 KiB
    float*  probs = (float*)(wsb + 132096);            // 4M fp32 = 16 MiB
    const size_t need = 132096 + (size_t)Bv * Lv * Ev * sizeof(float);

    precompute_kernel<<<dim3(257), dim3(256), 0, stream>>>(Wq, Wk, bq, Mb, rv);

    if (ws_size >= need) {
        edge_main<true><<<dim3(Bv * Lv), dim3(256), 0, stream>>>(
            hs, eidx, ew, skip, Mb, rv, probs);
        output_kernel<<<dim3(16, 16, 4), dim3(256), 0, stream>>>(
            probs, eidx, ew, skip, (float*)d_out);
    } else {
        float* out_ew = (float*)d_out + 2 * EI_PLANE;
        edge_main<false><<<dim3(Bv * Lv), dim3(256), 0, stream>>>(
            hs, eidx, ew, skip, Mb, rv, out_ew);
        ei_kernel<<<dim3(2 * BE), dim3(256), 0, stream>>>(eidx, (float*)d_out);
    }
}